// Round 5
// baseline (253.871 us; speedup 1.0000x reference)
//
#include <hip/hip_runtime.h>

typedef _Float16 half8 __attribute__((ext_vector_type(8)));
typedef float floatx4 __attribute__((ext_vector_type(4)));
typedef float f32x4 __attribute__((ext_vector_type(4)));
typedef unsigned int uint4v __attribute__((ext_vector_type(4)));

#define B_DIM 8
#define C_DIM 64
#define T_DIM 128
#define N_DIM 207
#define O_DIM 64
#define CSTR  (T_DIM * N_DIM)

// ---------------------------------------------------------------------------
// Kernel 0: pack Wq|Wk|Wv (fp32 [64 o][64 c]) -> fp16 in d_ws. [arr][o][c].
// ---------------------------------------------------------------------------
__global__ void pack_w(const float* __restrict__ Wq,
                       const float* __restrict__ Wk,
                       const float* __restrict__ Wv,
                       _Float16* __restrict__ ws)
{
    int i = threadIdx.x + blockIdx.x * blockDim.x;
    const int per = O_DIM * C_DIM;          // 4096
    for (int m = i; m < 3 * per; m += blockDim.x * gridDim.x) {
        int arr = m / per, rem = m % per;
        const float* W = (arr == 0) ? Wq : (arr == 1) ? Wk : Wv;
        ws[m] = (_Float16)W[rem];
    }
}

// ---------------------------------------------------------------------------
// Main: fully-unrolled t-marching MFMA kernel, 2 rows per superstep.
//  * 11 supersteps (2 t-rows each) -> 11 barriers instead of 22; two
//    independent row-pipelines (ds_read/cvt/MFMA) per barrier interval.
//  * global_load_lds staging, 2 double-row LDS buffers (48KB), 1-superstep
//    -ahead prefetch; exact vmcnt keep-suffix table (s<=3: 0, s>=4: 8).
//  * bijective XCD swizzle: 832 = 8 x 104; XCD x owns batch x, nb fastest
//    -> straddle/halo become L2 hits (round-4 verified: FETCH 310->114MB).
//  * circular K/V/Q windows with literal indices (zero register moves).
// ---------------------------------------------------------------------------

#define GLDS(gp_, lp_)                                                       \
    __builtin_amdgcn_global_load_lds(                                        \
        (const __attribute__((address_space(1))) void*)(gp_),                \
        (__attribute__((address_space(3))) void*)(lp_), 4, 0, 0)

// stage one t-row (q,k,v) into buffer P_, row-slot R_: 12 loads per wave
#define STAGE(tg_, P_, R_)                                                   \
    {                                                                        \
        const int tcl_  = min(max((tg_), 0), T_DIM - 1);                     \
        const int toff_ = tcl_ * N_DIM;                                      \
        _Pragma("unroll")                                                    \
        for (int arr_ = 0; arr_ < 3; ++arr_) {                               \
            const float* ab_ = (arr_ == 0) ? qb2 : (arr_ == 1) ? kb2 : vb2;  \
            _Pragma("unroll")                                                \
            for (int i_ = 0; i_ < 4; ++i_) {                                 \
                GLDS(ab_ + toff_ + col_off[i_],                              \
                     &xls[P_][R_][arr_][wv * 4 + i_][0][0]);                 \
            }                                                                \
        }                                                                    \
    }

// build f16 MFMA B-fragment (8 c-values for lane column nq) from f32 LDS
#define MKFRAG(P_, R_, arr_, kk_, dst_)                                      \
    {                                                                        \
        const float* ch_ = &xls[P_][R_][arr_][qd * 2 + (kk_) * 8][nq][0];    \
        f32x4 A_ = *(const f32x4*)(ch_);                                     \
        f32x4 B_ = *(const f32x4*)(ch_ + 64);                                \
        uint4v t_;                                                           \
        t_[0] = __builtin_bit_cast(unsigned int, __builtin_amdgcn_cvt_pkrtz(A_[0], A_[1])); \
        t_[1] = __builtin_bit_cast(unsigned int, __builtin_amdgcn_cvt_pkrtz(A_[2], A_[3])); \
        t_[2] = __builtin_bit_cast(unsigned int, __builtin_amdgcn_cvt_pkrtz(B_[0], B_[1])); \
        t_[3] = __builtin_bit_cast(unsigned int, __builtin_amdgcn_cvt_pkrtz(B_[2], B_[3])); \
        dst_ = __builtin_bit_cast(half8, t_);                                \
    }

#define MFMA16(a_, b_, c_) __builtin_amdgcn_mfma_f32_16x16x32_f16(a_, b_, c_, 0, 0, 0)

#define VMWAIT(N_) asm volatile("s_waitcnt vmcnt(" #N_ ")" ::: "memory")

// one t-row body, r_ / P_ / R_ are LITERAL constants (no barriers here)
#define ROWBODY(r_, P_, R_)                                                  \
    {                                                                        \
        half8 fk0, fk1, fv0, fv1;                                            \
        MKFRAG(P_, R_, 1, 0, fk0)  MKFRAG(P_, R_, 1, 1, fk1)                 \
        MKFRAG(P_, R_, 2, 0, fv0)  MKFRAG(P_, R_, 2, 1, fv1)                 \
        floatx4 aq = {0.f, 0.f, 0.f, 0.f};                                   \
        floatx4 ak = {0.f, 0.f, 0.f, 0.f};                                   \
        floatx4 av = {0.f, 0.f, 0.f, 0.f};                                   \
        ak = MFMA16(af[1][0], fk0, ak);  ak = MFMA16(af[1][1], fk1, ak);     \
        av = MFMA16(af[2][0], fv0, av);  av = MFMA16(af[2][1], fv1, av);     \
        if ((r_) >= 3 && (r_) <= 18) {                                       \
            half8 fq0, fq1;                                                  \
            MKFRAG(P_, R_, 0, 0, fq0)  MKFRAG(P_, R_, 0, 1, fq1)             \
            aq = MFMA16(af[0][0], fq0, aq);  aq = MFMA16(af[0][1], fq1, aq); \
        }                                                                    \
        const int  tg_   = t0 - 3 + (r_);                                    \
        const bool rowv_ = (tg_ >= 0) && (tg_ < T_DIM);                      \
        _Pragma("unroll")                                                    \
        for (int j = 0; j < 4; ++j) {                                        \
            Kw[j][(r_) % 7]  = rowv_ ? (ak[j] + bk_r[j]) : 0.f;              \
            Vw[j][(r_) % 7]  = rowv_ ? (av[j] + bv_r[j]) : 0.f;              \
            Qd4[j][(r_) % 4] = aq[j] + bq_r[j];                              \
        }                                                                    \
        if ((r_) >= 6) {                                                     \
            const int to_ = t0 + (r_) - 6;                                   \
            const int n_g = n0 + nq;                                         \
            if (n_g < N_DIM) {                                               \
                _Pragma("unroll")                                            \
                for (int j = 0; j < 4; ++j) {                                \
                    const float qv = Qd4[j][((r_) + 1) % 4] * 1.44269504f;   \
                    float s[7];                                              \
                    _Pragma("unroll")                                        \
                    for (int i = 0; i < 7; ++i)                              \
                        s[i] = qv * Kw[j][((r_) + 1 + i) % 7];               \
                    float mx = s[0];                                         \
                    _Pragma("unroll")                                        \
                    for (int i = 1; i < 7; ++i) mx = fmaxf(mx, s[i]);        \
                    float den = 0.f, num = 0.f;                              \
                    _Pragma("unroll")                                        \
                    for (int i = 0; i < 7; ++i) {                            \
                        float e = exp2f(s[i] - mx);                          \
                        den += e;                                            \
                        num = fmaf(e, Vw[j][((r_) + 1 + i) % 7], num);       \
                    }                                                        \
                    out[((size_t)(b * O_DIM + o0 + qd * 4 + j) * T_DIM + to_) * N_DIM + n_g] \
                        = num * __builtin_amdgcn_rcpf(den);                  \
                }                                                            \
            }                                                                \
        }                                                                    \
    }

// superstep s_: rows 2s, 2s+1 from buf s&1; stage rows 2s+2,2s+3 -> buf (s+1)&1.
// vmcnt keep-suffix at s: stores of superstep s-1 only (8 when s>=4, else 0).
#define SUPERSTEP(s_, N_)                                                    \
    {                                                                        \
        __builtin_amdgcn_sched_barrier(0);                                   \
        VMWAIT(N_);                                                          \
        __builtin_amdgcn_s_barrier();                                        \
        __builtin_amdgcn_sched_barrier(0);                                   \
        if ((s_) <= 9) {                                                     \
            STAGE(t0 - 1 + 2 * (s_), ((s_) + 1) & 1, 0)                      \
            STAGE(t0     + 2 * (s_), ((s_) + 1) & 1, 1)                      \
        }                                                                    \
        __builtin_amdgcn_sched_barrier(0);                                   \
        ROWBODY(2 * (s_),     (s_) & 1, 0)                                   \
        ROWBODY(2 * (s_) + 1, (s_) & 1, 1)                                   \
    }

__global__ __launch_bounds__(256, 3)
void attn_mfma(const float* __restrict__ q,
               const float* __restrict__ k,
               const float* __restrict__ v,
               const float* __restrict__ bq,
               const float* __restrict__ bk,
               const float* __restrict__ bv,
               const _Float16* __restrict__ wpk,
               float* __restrict__ out)
{
    // f32 staging: [buf][rowslot][arr][cb][n][cw] = 2*2*3*16*16*4*4B = 49152 B
    __shared__ __align__(16) float xls[2][2][3][16][16][4];

    const int tid  = threadIdx.x;
    const int lane = tid & 63;
    const int wv   = tid >> 6;        // wave = o-slice, also staging cb-group
    const int nq   = lane & 15;       // D col (n), A row (m)
    const int qd   = lane >> 4;       // quad

    // bijective XCD swizzle: 832 blocks = 8 XCDs x 104; XCD x owns batch x,
    // nb fastest within -> straddle/halo L2 sharing (round-4 verified).
    const int bid = (int)blockIdx.x + 13 * ((int)blockIdx.y + 8 * (int)blockIdx.z);
    const int swz = (bid & 7) * 104 + (bid >> 3);
    const int nb  = swz % 13;         // 0..12 (16 n each)
    const int tc  = (swz / 13) & 7;   // 0..7  (16 t each)
    const int b   = swz / 104;        // 0..7

    const int t0 = tc * 16;
    const int o0 = wv * 16;
    const int n0 = nb * 16;

    // ---- staging lane mapping: lane -> (n = lane>>2, cw = lane&3) ----
    const int cl   = lane & 3;
    const int nrow = lane >> 2;
    const int n_cl = min(n0 + nrow, N_DIM - 1);
    int col_off[4];
    #pragma unroll
    for (int i = 0; i < 4; ++i)
        col_off[i] = ((wv * 4 + i) * 4 + cl) * CSTR + n_cl;

    const float* qb2 = q + (size_t)b * C_DIM * CSTR;
    const float* kb2 = k + (size_t)b * C_DIM * CSTR;
    const float* vb2 = v + (size_t)b * C_DIM * CSTR;

    // ---- loop-invariant A-fragments: W[o0+m][k], m=nq, k=qd*8+j+kk*32 ----
    half8 af[3][2];
    #pragma unroll
    for (int arr = 0; arr < 3; ++arr)
        #pragma unroll
        for (int kk = 0; kk < 2; ++kk)
            af[arr][kk] = *(const half8*)(wpk + ((size_t)(arr * 64 + o0 + nq) * 64
                                                 + qd * 8 + kk * 32));

    // ---- bias per lane-reg: D row o_l = qd*4+reg ----
    float bq_r[4], bk_r[4], bv_r[4];
    #pragma unroll
    for (int j = 0; j < 4; ++j) {
        const int og = o0 + qd * 4 + j;
        bq_r[j] = bq[og]; bk_r[j] = bk[og]; bv_r[j] = bv[og];
    }

    // ---- circular windows (literal indices after unroll) ----
    float Kw[4][7], Vw[4][7], Qd4[4][4];
    #pragma unroll
    for (int j = 0; j < 4; ++j) {
        #pragma unroll
        for (int i = 0; i < 7; ++i) { Kw[j][i] = 0.f; Vw[j][i] = 0.f; }
        #pragma unroll
        for (int i = 0; i < 4; ++i) Qd4[j][i] = 0.f;
    }

    // ---- prologue: stage rows 0,1 (t0-3, t0-2) into buf 0 ----
    STAGE(t0 - 3, 0, 0)
    STAGE(t0 - 2, 0, 1)

    // ---- 11 supersteps; vmcnt = stores of previous superstep only ----
    SUPERSTEP( 0, 0)  SUPERSTEP( 1, 0)  SUPERSTEP( 2, 0)  SUPERSTEP( 3, 0)
    SUPERSTEP( 4, 8)  SUPERSTEP( 5, 8)  SUPERSTEP( 6, 8)  SUPERSTEP( 7, 8)
    SUPERSTEP( 8, 8)  SUPERSTEP( 9, 8)  SUPERSTEP(10, 8)
}

extern "C" void kernel_launch(void* const* d_in, const int* in_sizes, int n_in,
                              void* d_out, int out_size, void* d_ws, size_t ws_size,
                              hipStream_t stream)
{
    const float* q  = (const float*)d_in[0];
    const float* k  = (const float*)d_in[1];
    const float* v  = (const float*)d_in[2];
    const float* Wq = (const float*)d_in[3];
    const float* bq = (const float*)d_in[4];
    const float* Wk = (const float*)d_in[5];
    const float* bk = (const float*)d_in[6];
    const float* Wv = (const float*)d_in[7];
    const float* bv = (const float*)d_in[8];
    float* o = (float*)d_out;

    _Float16* ws_h = (_Float16*)d_ws;   // 24 KB used

    hipLaunchKernelGGL(pack_w, dim3(3), dim3(256), 0, stream, Wq, Wk, Wv, ws_h);

    dim3 grid(13, 8, B_DIM);            // (n-tile, t-chunk, b) = 832 blocks
    dim3 block(256);
    hipLaunchKernelGGL(attn_mfma, grid, block, 0, stream,
                       q, k, v, bq, bk, bv, (const _Float16*)ws_h, o);
}